// Round 10
// baseline (608.145 us; speedup 1.0000x reference)
//
#include <hip/hip_runtime.h>

#define SEQ 4096
#define NBATCH 256

__device__ __forceinline__ float sqf(float v) { return v * v; }
__device__ __forceinline__ float fexp2(float v) { return __builtin_amdgcn_exp2f(v); }
__device__ __forceinline__ float frcp(float v)  { return __builtin_amdgcn_rcpf(v); }

#define L2E 1.4426950408889634f

// order-preserving float<->uint key for atomicMax on floats
__device__ __forceinline__ unsigned fkey(float f) {
    const int b = __float_as_int(f);
    return (unsigned)(b ^ ((b >> 31) | 0x80000000));
}
__device__ __forceinline__ float fival(unsigned k) {
    const int b = (k & 0x80000000u) ? (int)(k ^ 0x80000000u) : (int)(~k);
    return __int_as_float(b);
}

// ---------------------------------------------------------------------------
// Kernel 0: pack ALL per-row constants into Wall[d][40][24]:
//   k 0..11  : folded 12-input Wx weights  (row-scaled)
//   k 12..21 : Whh[r][0..9]                (row-scaled)
//   k 22     : bih+bhh                     (row-scaled)
//   k 23     : 0
// Row scale sc_r = -log2e (i,f,o rows) or -2log2e (g rows) folds the
// activation pre-scale into every preactivation term.
// Also zero-initializes the MMu atomic-max buffer.
// ---------------------------------------------------------------------------
__global__ void wprep_kernel(
    const float* __restrict__ Wih_f, const float* __restrict__ bih_f,
    const float* __restrict__ bhh_f, const float* __restrict__ Whh_f,
    const float* __restrict__ Wih_r, const float* __restrict__ bih_r,
    const float* __restrict__ bhh_r, const float* __restrict__ Whh_r,
    float* __restrict__ Wall, unsigned* __restrict__ MMu)
{
    const int t = threadIdx.x;
    for (int i = t; i < NBATCH * 5; i += 256) MMu[i] = 0u;  // key 0 < any real
    if (t >= 80) return;
    const int d = t / 40, r = t % 40;
    const float* __restrict__ W   = (d ? Wih_r : Wih_f) + r * 24;
    const float* __restrict__ Whh = (d ? Whh_r : Whh_f) + r * 10;
    const float* __restrict__ bi  = d ? bih_r : bih_f;
    const float* __restrict__ bh  = d ? bhh_r : bhh_f;
    const float sc = (r >= 20 && r < 30) ? (-2.f * L2E) : (-L2E);
    float o[24];
    o[0]  = W[0] + W[1] + W[2] + W[3];                // v4s
    o[1]  = W[4] + W[5] + W[6] + W[7];                // v5s
    o[2]  = W[4];                                     // v5p
    o[3]  = W[8] + W[9] + W[10] + W[11];              // v6s
    o[4]  = W[8] + W[9];                              // v6p
    o[5]  = W[12] + W[13] + W[14] + W[15];            // v7s
    o[6]  = W[12] + W[13] + W[14];                    // v7p
    o[7]  = W[16] + W[17] + W[18] + W[19];            // v8s+v8p
    o[8]  = W[20]; o[9] = W[21]; o[10] = W[22]; o[11] = W[23];   // x0..x3
#pragma unroll
    for (int j = 0; j < 10; ++j) o[12 + j] = Whh[j];
    o[22] = bi[r] + bh[r];
    o[23] = 0.f;
    float* __restrict__ out = Wall + (d * 40 + r) * 24;
#pragma unroll
    for (int k = 0; k < 24; ++k) out[k] = o[k] * sc;
}

// ---------------------------------------------------------------------------
// Kernel 1a: per-batch conv max -> atomicMax on uint keys. 1024 blocks.
// ---------------------------------------------------------------------------
__global__ __launch_bounds__(256) void max_kernel(
    const float* __restrict__ x,
    const float* __restrict__ w4p, const float* __restrict__ w5p,
    const float* __restrict__ w6p, const float* __restrict__ w7p,
    const float* __restrict__ w8p,
    unsigned* __restrict__ MMu)
{
    const int b    = blockIdx.x >> 2;
    const int quar = blockIdx.x & 3;
    const int tid  = threadIdx.x;
    const float* __restrict__ xr = x + (size_t)b * (4 * SEQ);

    float W4[4], W5[5], W6[6], W7[7], W8[8];
#pragma unroll
    for (int k = 0; k < 4; ++k) W4[k] = w4p[k];
#pragma unroll
    for (int k = 0; k < 5; ++k) W5[k] = w5p[k];
#pragma unroll
    for (int k = 0; k < 6; ++k) W6[k] = w6p[k];
#pragma unroll
    for (int k = 0; k < 7; ++k) W7[k] = w7p[k];
#pragma unroll
    for (int k = 0; k < 8; ++k) W8[k] = w8p[k];

    float m4 = -3.4e38f, m5 = -3.4e38f, m6 = -3.4e38f, m7 = -3.4e38f, m8 = -3.4e38f;
    for (int i = quar * (SEQ / 4) + tid; i < (quar + 1) * (SEQ / 4); i += 256) {
        const float4 t0 = *reinterpret_cast<const float4*>(xr + 4 * i);
        const float xa0 = t0.x, xa1 = t0.y, xa2 = t0.z, xa3 = t0.w;
        const float c4 = xa0 * W4[0] + xa1 * W4[1] + xa2 * W4[2] + xa3 * W4[3];
        m4 = fmaxf(m4, c4);
        if (i < SEQ - 1) {
            const float4 t1 = *reinterpret_cast<const float4*>(xr + 4 * i + 4);
            const float xa4 = t1.x, xa5 = t1.y, xa6 = t1.z, xa7 = t1.w;
            const float c5 = xa0*W5[0]+xa1*W5[1]+xa2*W5[2]+xa3*W5[3]+xa4*W5[4];
            const float c6 = xa0*W6[0]+xa1*W6[1]+xa2*W6[2]+xa3*W6[3]+xa4*W6[4]+xa5*W6[5];
            const float c7 = xa0*W7[0]+xa1*W7[1]+xa2*W7[2]+xa3*W7[3]+xa4*W7[4]+xa5*W7[5]+xa6*W7[6];
            const float c8 = xa0*W8[0]+xa1*W8[1]+xa2*W8[2]+xa3*W8[3]+xa4*W8[4]+xa5*W8[5]+xa6*W8[6]+xa7*W8[7];
            m5 = fmaxf(m5, c5); m6 = fmaxf(m6, c6);
            m7 = fmaxf(m7, c7); m8 = fmaxf(m8, c8);
        }
    }
#pragma unroll
    for (int off = 32; off; off >>= 1) {
        m4 = fmaxf(m4, __shfl_down(m4, off));
        m5 = fmaxf(m5, __shfl_down(m5, off));
        m6 = fmaxf(m6, __shfl_down(m6, off));
        m7 = fmaxf(m7, __shfl_down(m7, off));
        m8 = fmaxf(m8, __shfl_down(m8, off));
    }
    __shared__ float wr[4][5];
    if ((tid & 63) == 0) {
        const int w = tid >> 6;
        wr[w][0] = m4; wr[w][1] = m5; wr[w][2] = m6; wr[w][3] = m7; wr[w][4] = m8;
    }
    __syncthreads();
    if (tid < 5) {
        const float m = fmaxf(fmaxf(wr[0][tid], wr[1][tid]),
                              fmaxf(wr[2][tid], wr[3][tid]));
        atomicMax(&MMu[b * 5 + tid], fkey(m));
    }
}

// ---------------------------------------------------------------------------
// Kernel 1b: winner-takes-all -> compressed 12-input rows, TRANSPOSED layout
// linT[s][b][16] = {v4s, v5s, v5p, v6s, v6p, v7s, v7p, v8s+v8p,
//                   x0, x1, x2, x3, xsum, 0,0,0}
// (s-major so the lane=chain LSTM reads are coalesced: the 4 consecutive
// 16 B stores per row still fill complete 64 B lines in L2.)
// ---------------------------------------------------------------------------
__global__ __launch_bounds__(256) void scatter_kernel(
    const float* __restrict__ x,
    const float* __restrict__ w4p, const float* __restrict__ w5p,
    const float* __restrict__ w6p, const float* __restrict__ w7p,
    const float* __restrict__ w8p,
    const unsigned* __restrict__ MMu,
    float* __restrict__ linT)
{
    const int b    = blockIdx.x >> 2;
    const int quar = blockIdx.x & 3;
    const int tid  = threadIdx.x;
    const float* __restrict__ xr = x + (size_t)b * (4 * SEQ);

    float W4[4], W5[5], W6[6], W7[7], W8[8];
#pragma unroll
    for (int k = 0; k < 4; ++k) W4[k] = w4p[k];
#pragma unroll
    for (int k = 0; k < 5; ++k) W5[k] = w5p[k];
#pragma unroll
    for (int k = 0; k < 6; ++k) W6[k] = w6p[k];
#pragma unroll
    for (int k = 0; k < 7; ++k) W7[k] = w7p[k];
#pragma unroll
    for (int k = 0; k < 8; ++k) W8[k] = w8p[k];

    const float M4 = fival(MMu[b * 5 + 0]), M5 = fival(MMu[b * 5 + 1]),
                M6 = fival(MMu[b * 5 + 2]), M7 = fival(MMu[b * 5 + 3]),
                M8 = fival(MMu[b * 5 + 4]);

    for (int s = quar * (SEQ / 4) + tid; s < (quar + 1) * (SEQ / 4); s += 256) {
        float xw[12];
        if (s > 0) {
            const float4 t = *reinterpret_cast<const float4*>(xr + 4 * s - 4);
            xw[0] = t.x; xw[1] = t.y; xw[2] = t.z; xw[3] = t.w;
        } else { xw[0] = xw[1] = xw[2] = xw[3] = 0.f; }
        {
            const float4 t = *reinterpret_cast<const float4*>(xr + 4 * s);
            xw[4] = t.x; xw[5] = t.y; xw[6] = t.z; xw[7] = t.w;
        }
        if (s < SEQ - 1) {
            const float4 t = *reinterpret_cast<const float4*>(xr + 4 * s + 4);
            xw[8] = t.x; xw[9] = t.y; xw[10] = t.z; xw[11] = t.w;
        } else { xw[8] = xw[9] = xw[10] = xw[11] = 0.f; }

        float c4s = 0.f, c5s = 0.f, c6s = 0.f, c7s = 0.f, c8s = 0.f;
        float c5p = 0.f, c6p = 0.f, c7p = 0.f, c8p = 0.f;
#pragma unroll
        for (int t = 0; t < 4; ++t) c4s += xw[4 + t] * W4[t];
#pragma unroll
        for (int t = 0; t < 5; ++t) { c5s += xw[4 + t] * W5[t]; c5p += xw[t] * W5[t]; }
#pragma unroll
        for (int t = 0; t < 6; ++t) { c6s += xw[4 + t] * W6[t]; c6p += xw[t] * W6[t]; }
#pragma unroll
        for (int t = 0; t < 7; ++t) { c7s += xw[4 + t] * W7[t]; c7p += xw[t] * W7[t]; }
#pragma unroll
        for (int t = 0; t < 8; ++t) { c8s += xw[4 + t] * W8[t]; c8p += xw[t] * W8[t]; }

        const bool oks = (s < SEQ - 1);
        const bool okp = (s > 0);
        const float v4s = sqf(c4s + M4);
        const float v5s = oks ? sqf(c5s + M5) : 0.f;
        const float v6s = oks ? sqf(c6s + M6) : 0.f;
        const float v7s = oks ? sqf(c7s + M7) : 0.f;
        const float v8s = oks ? sqf(c8s + M8) : 0.f;
        const float v5p = okp ? sqf(c5p + M5) : 0.f;
        const float v6p = okp ? sqf(c6p + M6) : 0.f;
        const float v7p = okp ? sqf(c7p + M7) : 0.f;
        const float v8p = okp ? sqf(c8p + M8) : 0.f;

        const float xsum = (xw[4] + xw[5]) + (xw[6] + xw[7]);
        float4* op = reinterpret_cast<float4*>(linT + ((size_t)s * NBATCH + b) * 16);
        op[0] = make_float4(v4s, v5s, v5p, v6s);
        op[1] = make_float4(v6p, v7s, v7p, v8s + v8p);
        op[2] = make_float4(xw[4], xw[5], xw[6], xw[7]);
        op[3] = make_float4(xsum, 0.f, 0.f, 0.f);
    }
}

// ---------------------------------------------------------------------------
// Kernel 2: SIMD-across-chains segmented bidirectional LSTM.
// lane = chain (batch b0+lane); each lane holds the FULL state h[10], cs[10]
// in registers. No LDS, no cross-lane ops. Weights are wave-uniform
// (Wall[d][r][24]) -> scalar s_loads off the VALU pipe.
// K = 128 segments/chain: grid = 128 seg x 2 dir x 4 bgroups = 1024 blocks
// x 64 thr = 1 wave/SIMD. Each wave: 64 warm + 32 owned = 96 serial steps.
// Warmup contraction (E[ln f] ~ -0.7/step -> err ~e^-45) is far inside the
// 128-step margin validated absmax=0.0 in r5-r9. accS reset after warmup;
// seg 0 also resets state (its warm rows are clamped garbage).
// Per step: 4 coalesced b128 loads (depth-2 prefetch), 40 rows x 23-term
// preactivation (folded inputs + Whh + bias, all pre-scaled), 10 in-lane
// LSTM unit updates (cs-space cell state).
// ---------------------------------------------------------------------------
__global__ __launch_bounds__(64) void lstm_kernel(
    const float* __restrict__ linT,
    const float* __restrict__ Wall,
    float* __restrict__ P)
{
    const int bg   = blockIdx.x & 3;
    const int d    = (blockIdx.x >> 2) & 1;
    const int seg  = blockIdx.x >> 3;          // 0..127
    const int lane = threadIdx.x;
    const int b    = bg * 64 + lane;

    const int s0 = seg * 32 - 64;              // 64 warm + 32 owned
    const float* __restrict__ W = Wall + d * 40 * 24;   // wave-uniform

    auto rowaddr = [&](int t) {
        int sp = s0 + t;
        sp = sp < 0 ? 0 : sp;
        const int pos = d ? (SEQ - 1 - sp) : sp;
        return reinterpret_cast<const float4*>(linT + ((size_t)pos * NBATCH + b) * 16);
    };

    float4 cur[4], nxt[4];
    { const float4* a = rowaddr(0); cur[0]=a[0]; cur[1]=a[1]; cur[2]=a[2]; cur[3]=a[3]; }
    { const float4* a = rowaddr(1); nxt[0]=a[0]; nxt[1]=a[1]; nxt[2]=a[2]; nxt[3]=a[3]; }

    float h[10], cs[10];
#pragma unroll
    for (int j = 0; j < 10; ++j) { h[j] = 0.f; cs[j] = 0.f; }
    float accS = 0.f;

    for (int t = 0; t < 96; ++t) {
        float v[12];
        v[0] = cur[0].x; v[1] = cur[0].y; v[2]  = cur[0].z; v[3]  = cur[0].w;
        v[4] = cur[1].x; v[5] = cur[1].y; v[6]  = cur[1].z; v[7]  = cur[1].w;
        v[8] = cur[2].x; v[9] = cur[2].y; v[10] = cur[2].z; v[11] = cur[2].w;
        const float xs = cur[3].x;
        cur[0] = nxt[0]; cur[1] = nxt[1]; cur[2] = nxt[2]; cur[3] = nxt[3];
        {
            const int tp = (t + 2 < 96) ? t + 2 : 95;
            const float4* a = rowaddr(tp);
            nxt[0] = a[0]; nxt[1] = a[1]; nxt[2] = a[2]; nxt[3] = a[3];
        }

        float hn[10];
#pragma unroll
        for (int j = 0; j < 10; ++j) {
            float e[4];
#pragma unroll
            for (int g = 0; g < 4; ++g) {
                const float* __restrict__ w = W + (g * 10 + j) * 24;
                float a0 = w[22], a1 = 0.f, a2 = 0.f, a3 = 0.f;
                a0 = fmaf(v[0],  w[0],  a0); a1 = fmaf(v[1],  w[1],  a1);
                a2 = fmaf(v[2],  w[2],  a2); a3 = fmaf(v[3],  w[3],  a3);
                a0 = fmaf(v[4],  w[4],  a0); a1 = fmaf(v[5],  w[5],  a1);
                a2 = fmaf(v[6],  w[6],  a2); a3 = fmaf(v[7],  w[7],  a3);
                a0 = fmaf(v[8],  w[8],  a0); a1 = fmaf(v[9],  w[9],  a1);
                a2 = fmaf(v[10], w[10], a2); a3 = fmaf(v[11], w[11], a3);
                a0 = fmaf(h[0],  w[12], a0); a1 = fmaf(h[1],  w[13], a1);
                a2 = fmaf(h[2],  w[14], a2); a3 = fmaf(h[3],  w[15], a3);
                a0 = fmaf(h[4],  w[16], a0); a1 = fmaf(h[5],  w[17], a1);
                a2 = fmaf(h[6],  w[18], a2); a3 = fmaf(h[7],  w[19], a3);
                a0 = fmaf(h[8],  w[20], a0); a1 = fmaf(h[9],  w[21], a1);
                e[g] = (a0 + a1) + (a2 + a3);
            }
            const float ig = frcp(1.f + fexp2(e[0]));
            const float fg = frcp(1.f + fexp2(e[1]));
            const float tg = fmaf(frcp(1.f + fexp2(e[2])), 2.f, -1.f);
            const float og = frcp(1.f + fexp2(e[3]));
            cs[j] = fmaf(fg, cs[j], (ig * (-2.f * L2E)) * tg);  // cs = -2log2e*c
            const float rc = frcp(1.f + fexp2(cs[j]));
            hn[j] = og * fmaf(2.f, rc, -1.f);                   // o * tanh(c)
        }
        const float hsum = (((hn[0] + hn[1]) + (hn[2] + hn[3])) +
                            ((hn[4] + hn[5]) + (hn[6] + hn[7]))) + (hn[8] + hn[9]);
        accS = fmaf(xs, hsum, accS);
#pragma unroll
        for (int j = 0; j < 10; ++j) h[j] = hn[j];

        if (t == 63) {                         // end of warmup
            accS = 0.f;
            if (seg == 0) {
#pragma unroll
                for (int j = 0; j < 10; ++j) { h[j] = 0.f; cs[j] = 0.f; }
            }
        }
    }

    P[(size_t)seg * 512 + d * 256 + b] = accS;
}

// ---------------------------------------------------------------------------
// Kernel 3: out[b] = sigmoid( sum over 128 segments x 2 directions )
// ---------------------------------------------------------------------------
__global__ __launch_bounds__(256) void final_kernel(const float* __restrict__ P,
                                                    float* __restrict__ out)
{
    const int b = threadIdx.x;
    float v = 0.f;
    for (int seg = 0; seg < 128; ++seg)
        v += P[(size_t)seg * 512 + b] + P[(size_t)seg * 512 + 256 + b];
    out[b] = frcp(1.f + fexp2(-v * L2E));
}

extern "C" void kernel_launch(void* const* d_in, const int* in_sizes, int n_in,
                              void* d_out, int out_size, void* d_ws, size_t ws_size,
                              hipStream_t stream)
{
    const float* x     = (const float*)d_in[0];
    const float* w4    = (const float*)d_in[1];
    const float* w5    = (const float*)d_in[2];
    const float* w6    = (const float*)d_in[3];
    const float* w7    = (const float*)d_in[4];
    const float* w8    = (const float*)d_in[5];
    const float* Wih_f = (const float*)d_in[6];
    const float* Whh_f = (const float*)d_in[7];
    const float* bih_f = (const float*)d_in[8];
    const float* bhh_f = (const float*)d_in[9];
    const float* Wih_r = (const float*)d_in[10];
    const float* Whh_r = (const float*)d_in[11];
    const float* bih_r = (const float*)d_in[12];
    const float* bhh_r = (const float*)d_in[13];

    // ws (fp32): linT [4096][256][16] (64MB) | P [128*512] | MMu[1280] | Wall[1920]
    float*    linT = (float*)d_ws;
    float*    P    = linT + (size_t)SEQ * NBATCH * 16;
    unsigned* MMu  = (unsigned*)(P + 128 * 512);
    float*    Wal  = (float*)(MMu + 1280);

    wprep_kernel<<<1, 256, 0, stream>>>(Wih_f, bih_f, bhh_f, Whh_f,
                                        Wih_r, bih_r, bhh_r, Whh_r, Wal, MMu);
    max_kernel<<<4 * NBATCH, 256, 0, stream>>>(x, w4, w5, w6, w7, w8, MMu);
    scatter_kernel<<<4 * NBATCH, 256, 0, stream>>>(x, w4, w5, w6, w7, w8, MMu, linT);
    lstm_kernel<<<1024, 64, 0, stream>>>(linT, Wal, P);
    final_kernel<<<1, NBATCH, 0, stream>>>(P, (float*)d_out);
}

// Round 11
// 509.656 us; speedup vs baseline: 1.1932x; 1.1932x over previous
//
#include <hip/hip_runtime.h>

#define SEQ 4096
#define NBATCH 256

typedef _Float16 half8 __attribute__((ext_vector_type(8)));

__device__ __forceinline__ float sqf(float v) { return v * v; }
__device__ __forceinline__ float fexp2(float v) { return __builtin_amdgcn_exp2f(v); }
__device__ __forceinline__ float frcp(float v)  { return __builtin_amdgcn_rcpf(v); }

#define L2E 1.4426950408889634f

// order-preserving float<->uint key for atomicMax on floats
__device__ __forceinline__ unsigned fkey(float f) {
    const int b = __float_as_int(f);
    return (unsigned)(b ^ ((b >> 31) | 0x80000000));
}
__device__ __forceinline__ float fival(unsigned k) {
    const int b = (k & 0x80000000u) ? (int)(k ^ 0x80000000u) : (int)(~k);
    return __int_as_float(b);
}

// ---------------------------------------------------------------------------
// Kernel 0: fold the 24-wide input matvec into 12 inputs + bias, pre-scaled
// by the row's activation pre-scale (-log2e; -2log2e for g rows).
// Wp[d][r][16] = {w0..w11, bias, 0,0,0}. Also zero-inits MMu.
// ---------------------------------------------------------------------------
__global__ void wprep_kernel(
    const float* __restrict__ Wih_f, const float* __restrict__ bih_f,
    const float* __restrict__ bhh_f,
    const float* __restrict__ Wih_r, const float* __restrict__ bih_r,
    const float* __restrict__ bhh_r,
    float* __restrict__ Wp, unsigned* __restrict__ MMu)
{
    const int t = threadIdx.x;
    for (int i = t; i < NBATCH * 5; i += 256) MMu[i] = 0u;  // key 0 < any real
    if (t >= 80) return;
    const int d = t / 40, r = t % 40;
    const float* __restrict__ W  = (d ? Wih_r : Wih_f) + r * 24;
    const float* __restrict__ bi = d ? bih_r : bih_f;
    const float* __restrict__ bh = d ? bhh_r : bhh_f;
    const float sc = (r >= 20 && r < 30) ? (-2.f * L2E) : (-L2E);
    float o[13];
    o[0]  = W[0] + W[1] + W[2] + W[3];                // v4s
    o[1]  = W[4] + W[5] + W[6] + W[7];                // v5s
    o[2]  = W[4];                                     // v5p
    o[3]  = W[8] + W[9] + W[10] + W[11];              // v6s
    o[4]  = W[8] + W[9];                              // v6p
    o[5]  = W[12] + W[13] + W[14] + W[15];            // v7s
    o[6]  = W[12] + W[13] + W[14];                    // v7p
    o[7]  = W[16] + W[17] + W[18] + W[19];            // v8s+v8p
    o[8]  = W[20]; o[9] = W[21]; o[10] = W[22]; o[11] = W[23];   // x0..x3
    o[12] = bi[r] + bh[r];
    float* __restrict__ out = Wp + (d * 40 + r) * 16;
#pragma unroll
    for (int k = 0; k < 13; ++k) out[k] = o[k] * sc;
    out[13] = 0.f; out[14] = 0.f; out[15] = 0.f;
}

// ---------------------------------------------------------------------------
// Kernel 1: per-batch conv max -> atomicMax on uint keys. 1024 blocks.
// ---------------------------------------------------------------------------
__global__ __launch_bounds__(256) void max_kernel(
    const float* __restrict__ x,
    const float* __restrict__ w4p, const float* __restrict__ w5p,
    const float* __restrict__ w6p, const float* __restrict__ w7p,
    const float* __restrict__ w8p,
    unsigned* __restrict__ MMu)
{
    const int b    = blockIdx.x >> 2;
    const int quar = blockIdx.x & 3;
    const int tid  = threadIdx.x;
    const float* __restrict__ xr = x + (size_t)b * (4 * SEQ);

    float W4[4], W5[5], W6[6], W7[7], W8[8];
#pragma unroll
    for (int k = 0; k < 4; ++k) W4[k] = w4p[k];
#pragma unroll
    for (int k = 0; k < 5; ++k) W5[k] = w5p[k];
#pragma unroll
    for (int k = 0; k < 6; ++k) W6[k] = w6p[k];
#pragma unroll
    for (int k = 0; k < 7; ++k) W7[k] = w7p[k];
#pragma unroll
    for (int k = 0; k < 8; ++k) W8[k] = w8p[k];

    float m4 = -3.4e38f, m5 = -3.4e38f, m6 = -3.4e38f, m7 = -3.4e38f, m8 = -3.4e38f;
    for (int i = quar * (SEQ / 4) + tid; i < (quar + 1) * (SEQ / 4); i += 256) {
        const float4 t0 = *reinterpret_cast<const float4*>(xr + 4 * i);
        const float xa0 = t0.x, xa1 = t0.y, xa2 = t0.z, xa3 = t0.w;
        const float c4 = xa0 * W4[0] + xa1 * W4[1] + xa2 * W4[2] + xa3 * W4[3];
        m4 = fmaxf(m4, c4);
        if (i < SEQ - 1) {
            const float4 t1 = *reinterpret_cast<const float4*>(xr + 4 * i + 4);
            const float xa4 = t1.x, xa5 = t1.y, xa6 = t1.z, xa7 = t1.w;
            const float c5 = xa0*W5[0]+xa1*W5[1]+xa2*W5[2]+xa3*W5[3]+xa4*W5[4];
            const float c6 = xa0*W6[0]+xa1*W6[1]+xa2*W6[2]+xa3*W6[3]+xa4*W6[4]+xa5*W6[5];
            const float c7 = xa0*W7[0]+xa1*W7[1]+xa2*W7[2]+xa3*W7[3]+xa4*W7[4]+xa5*W7[5]+xa6*W7[6];
            const float c8 = xa0*W8[0]+xa1*W8[1]+xa2*W8[2]+xa3*W8[3]+xa4*W8[4]+xa5*W8[5]+xa6*W8[6]+xa7*W8[7];
            m5 = fmaxf(m5, c5); m6 = fmaxf(m6, c6);
            m7 = fmaxf(m7, c7); m8 = fmaxf(m8, c8);
        }
    }
#pragma unroll
    for (int off = 32; off; off >>= 1) {
        m4 = fmaxf(m4, __shfl_down(m4, off));
        m5 = fmaxf(m5, __shfl_down(m5, off));
        m6 = fmaxf(m6, __shfl_down(m6, off));
        m7 = fmaxf(m7, __shfl_down(m7, off));
        m8 = fmaxf(m8, __shfl_down(m8, off));
    }
    __shared__ float wr[4][5];
    if ((tid & 63) == 0) {
        const int w = tid >> 6;
        wr[w][0] = m4; wr[w][1] = m5; wr[w][2] = m6; wr[w][3] = m7; wr[w][4] = m8;
    }
    __syncthreads();
    if (tid < 5) {
        const float m = fmaxf(fmaxf(wr[0][tid], wr[1][tid]),
                              fmaxf(wr[2][tid], wr[3][tid]));
        atomicMax(&MMu[b * 5 + tid], fkey(m));
    }
}

// ---------------------------------------------------------------------------
// Kernel 2: conv winner-takes-all + FULL input-side gate preactivation for
// one direction d, stored fp16, s-mirrored for d=1:
//   gp[s'][b][r] (r = gate*10+unit, 40 halves = 80 B/row, pre-scaled,
//                 bias folded)  and  xs[s'][b] (fp32).
// Grid 4096 blocks (= s) x 256 thr (= b). Launched once per direction,
// reusing the same 84 MB buffer (ws budget).
// ---------------------------------------------------------------------------
__global__ __launch_bounds__(256) void gprep_kernel(
    const float* __restrict__ x,
    const float* __restrict__ w4p, const float* __restrict__ w5p,
    const float* __restrict__ w6p, const float* __restrict__ w7p,
    const float* __restrict__ w8p,
    const unsigned* __restrict__ MMu,
    const float* __restrict__ Wp,
    _Float16* __restrict__ gp, float* __restrict__ xs, int d)
{
    const int s = blockIdx.x;
    const int b = threadIdx.x;
    const float* __restrict__ xr = x + (size_t)b * (4 * SEQ);

    float W4[4], W5[5], W6[6], W7[7], W8[8];
#pragma unroll
    for (int k = 0; k < 4; ++k) W4[k] = w4p[k];
#pragma unroll
    for (int k = 0; k < 5; ++k) W5[k] = w5p[k];
#pragma unroll
    for (int k = 0; k < 6; ++k) W6[k] = w6p[k];
#pragma unroll
    for (int k = 0; k < 7; ++k) W7[k] = w7p[k];
#pragma unroll
    for (int k = 0; k < 8; ++k) W8[k] = w8p[k];

    const float M4 = fival(MMu[b * 5 + 0]), M5 = fival(MMu[b * 5 + 1]),
                M6 = fival(MMu[b * 5 + 2]), M7 = fival(MMu[b * 5 + 3]),
                M8 = fival(MMu[b * 5 + 4]);

    float xw[12];
    if (s > 0) {
        const float4 t = *reinterpret_cast<const float4*>(xr + 4 * s - 4);
        xw[0] = t.x; xw[1] = t.y; xw[2] = t.z; xw[3] = t.w;
    } else { xw[0] = xw[1] = xw[2] = xw[3] = 0.f; }
    {
        const float4 t = *reinterpret_cast<const float4*>(xr + 4 * s);
        xw[4] = t.x; xw[5] = t.y; xw[6] = t.z; xw[7] = t.w;
    }
    if (s < SEQ - 1) {
        const float4 t = *reinterpret_cast<const float4*>(xr + 4 * s + 4);
        xw[8] = t.x; xw[9] = t.y; xw[10] = t.z; xw[11] = t.w;
    } else { xw[8] = xw[9] = xw[10] = xw[11] = 0.f; }

    float c4s = 0.f, c5s = 0.f, c6s = 0.f, c7s = 0.f, c8s = 0.f;
    float c5p = 0.f, c6p = 0.f, c7p = 0.f, c8p = 0.f;
#pragma unroll
    for (int t = 0; t < 4; ++t) c4s += xw[4 + t] * W4[t];
#pragma unroll
    for (int t = 0; t < 5; ++t) { c5s += xw[4 + t] * W5[t]; c5p += xw[t] * W5[t]; }
#pragma unroll
    for (int t = 0; t < 6; ++t) { c6s += xw[4 + t] * W6[t]; c6p += xw[t] * W6[t]; }
#pragma unroll
    for (int t = 0; t < 7; ++t) { c7s += xw[4 + t] * W7[t]; c7p += xw[t] * W7[t]; }
#pragma unroll
    for (int t = 0; t < 8; ++t) { c8s += xw[4 + t] * W8[t]; c8p += xw[t] * W8[t]; }

    const bool oks = (s < SEQ - 1);
    const bool okp = (s > 0);
    const float v4s = sqf(c4s + M4);
    const float v5s = oks ? sqf(c5s + M5) : 0.f;
    const float v6s = oks ? sqf(c6s + M6) : 0.f;
    const float v7s = oks ? sqf(c7s + M7) : 0.f;
    const float v8s = oks ? sqf(c8s + M8) : 0.f;
    const float v5p = okp ? sqf(c5p + M5) : 0.f;
    const float v6p = okp ? sqf(c6p + M6) : 0.f;
    const float v7p = okp ? sqf(c7p + M7) : 0.f;
    const float v8p = okp ? sqf(c8p + M8) : 0.f;

    float vv[12];
    vv[0] = v4s; vv[1] = v5s; vv[2]  = v5p;   vv[3]  = v6s;
    vv[4] = v6p; vv[5] = v7s; vv[6]  = v7p;   vv[7]  = v8s + v8p;
    vv[8] = xw[4]; vv[9] = xw[5]; vv[10] = xw[6]; vv[11] = xw[7];

    const int sp = d ? (SEQ - 1 - s) : s;
    xs[(size_t)sp * NBATCH + b] = (xw[4] + xw[5]) + (xw[6] + xw[7]);

    const float* __restrict__ Wd = Wp + d * 640;   // wave-uniform -> s_loads
    float er[40];
#pragma unroll
    for (int r = 0; r < 40; ++r) {
        float a0 = Wd[r * 16 + 12], a1 = 0.f, a2 = 0.f, a3 = 0.f;
#pragma unroll
        for (int k = 0; k < 12; k += 4) {
            a0 = fmaf(vv[k + 0], Wd[r * 16 + k + 0], a0);
            a1 = fmaf(vv[k + 1], Wd[r * 16 + k + 1], a1);
            a2 = fmaf(vv[k + 2], Wd[r * 16 + k + 2], a2);
            a3 = fmaf(vv[k + 3], Wd[r * 16 + k + 3], a3);
        }
        er[r] = (a0 + a1) + (a2 + a3);
    }
    half8* op = reinterpret_cast<half8*>(gp + ((size_t)sp * NBATCH + b) * 40);
#pragma unroll
    for (int q = 0; q < 5; ++q) {
        half8 o;
#pragma unroll
        for (int e = 0; e < 8; ++e) o[e] = (_Float16)er[q * 8 + e];
        op[q] = o;
    }
}

// ---------------------------------------------------------------------------
// Kernel 3: lane=chain LSTM over precomputed fp16 preactivations, one dir.
// Grid = 256 segs x 4 bgroups = 1024 blocks x 64 thr = 1 wave/SIMD.
// Each lane: one chain-segment, full state h[10]/cs[10] in registers,
// Whh (400 floats, pre-scaled) loaded ONCE into VGPRs (launch_bounds(64,1)
// -> 512-VGPR budget; no in-loop weight traffic = r10's failure removed).
// Segment owns 16 steps; segs 0..4 start at s=0 with exact short history,
// segs >=5 use 64-step warmup from (h,c)=0 (contraction validated r5-r9).
// Per step: 5 coalesced b128 loads (40 halves) + 1 xs load (depth-1
// prefetch), 40 cvt, 400 fma, 10 in-lane unit updates. No LDS.
// ---------------------------------------------------------------------------
__global__ __launch_bounds__(64, 1) void lstm_kernel(
    const _Float16* __restrict__ gp,
    const float* __restrict__ xs,
    const float* __restrict__ Whh,
    float* __restrict__ P)
{
    const int seg  = blockIdx.x >> 2;          // 0..255
    const int bg   = blockIdx.x & 3;
    const int lane = threadIdx.x;
    const int b    = bg * 64 + lane;

    int sStart = seg * 16 - 64;
    int warm   = 64;
    if (sStart < 0) { warm = seg * 16; sStart = 0; }   // exact short history
    const int L = warm + 16;

    // Whh pre-scaled, resident in VGPRs for the whole kernel
    float w[400];
#pragma unroll
    for (int r = 0; r < 40; ++r) {
        const float sc = (r >= 20 && r < 30) ? (-2.f * L2E) : (-L2E);
#pragma unroll
        for (int k = 0; k < 10; ++k) w[r * 10 + k] = Whh[r * 10 + k] * sc;
    }

    const half8* __restrict__ gbase =
        reinterpret_cast<const half8*>(gp + ((size_t)sStart * NBATCH + b) * 40);
    const float* __restrict__ xsb = xs + (size_t)sStart * NBATCH + b;

    half8 cur[5];
#pragma unroll
    for (int i = 0; i < 5; ++i) cur[i] = gbase[i];
    float xc = xsb[0];

    float h[10], cs[10];
#pragma unroll
    for (int j = 0; j < 10; ++j) { h[j] = 0.f; cs[j] = 0.f; }
    float accS = 0.f;

    for (int t = 0; t < L; ++t) {
        // unpack this step's preacts, then immediately prefetch next row
        float v[40];
#pragma unroll
        for (int i = 0; i < 5; ++i)
#pragma unroll
            for (int e = 0; e < 8; ++e) v[i * 8 + e] = (float)cur[i][e];
        const float sxv = xc;
        {
            const int tn = (t + 1 < L) ? t + 1 : t;
            const half8* rp = gbase + (size_t)tn * (NBATCH * 5);
#pragma unroll
            for (int i = 0; i < 5; ++i) cur[i] = rp[i];
            xc = xsb[(size_t)tn * NBATCH];
        }
        // recurrent matvec: v[r] += sum_k h[k]*w[r][k]  (400 fma, all VGPR)
#pragma unroll
        for (int j = 0; j < 10; ++j) {
#pragma unroll
            for (int k = 0; k < 10; ++k) {
                v[j]      = fmaf(h[k], w[j * 10 + k],        v[j]);
                v[10 + j] = fmaf(h[k], w[(10 + j) * 10 + k], v[10 + j]);
                v[20 + j] = fmaf(h[k], w[(20 + j) * 10 + k], v[20 + j]);
                v[30 + j] = fmaf(h[k], w[(30 + j) * 10 + k], v[30 + j]);
            }
        }
        // unit updates (h reads all done -> update in place)
        float hsum = 0.f;
#pragma unroll
        for (int j = 0; j < 10; ++j) {
            const float ig = frcp(1.f + fexp2(v[j]));
            const float fg = frcp(1.f + fexp2(v[10 + j]));
            const float tg = fmaf(frcp(1.f + fexp2(v[20 + j])), 2.f, -1.f);
            const float og = frcp(1.f + fexp2(v[30 + j]));
            cs[j] = fmaf(fg, cs[j], (ig * (-2.f * L2E)) * tg);   // cs=-2L2E*c
            h[j]  = og * fmaf(2.f, frcp(1.f + fexp2(cs[j])), -1.f);
            hsum += h[j];
        }
        accS = fmaf(sxv, hsum, accS);
        if (t + 1 == warm) accS = 0.f;         // drop warmup contributions
    }

    P[seg * NBATCH + b] = accS;
}

// ---------------------------------------------------------------------------
// Kernel 4: out[b] = sigmoid( sum over 2 dirs x 256 segments )
// ---------------------------------------------------------------------------
__global__ __launch_bounds__(256) void final_kernel(const float* __restrict__ P,
                                                    float* __restrict__ out)
{
    const int b = threadIdx.x;
    float v = 0.f;
    for (int i = 0; i < 512; ++i) v += P[(size_t)i * NBATCH + b];
    out[b] = frcp(1.f + fexp2(-v * L2E));
}

extern "C" void kernel_launch(void* const* d_in, const int* in_sizes, int n_in,
                              void* d_out, int out_size, void* d_ws, size_t ws_size,
                              hipStream_t stream)
{
    const float* x     = (const float*)d_in[0];
    const float* w4    = (const float*)d_in[1];
    const float* w5    = (const float*)d_in[2];
    const float* w6    = (const float*)d_in[3];
    const float* w7    = (const float*)d_in[4];
    const float* w8    = (const float*)d_in[5];
    const float* Wih_f = (const float*)d_in[6];
    const float* Whh_f = (const float*)d_in[7];
    const float* bih_f = (const float*)d_in[8];
    const float* bhh_f = (const float*)d_in[9];
    const float* Wih_r = (const float*)d_in[10];
    const float* Whh_r = (const float*)d_in[11];
    const float* bih_r = (const float*)d_in[12];
    const float* bhh_r = (const float*)d_in[13];

    // ws: gp fp16 [4096][256][40] (83.9MB, reused per dir) | xs fp32 [4096][256]
    //     | P [2][256][256] | MMu[1280] | Wp[1280]   total ~88.7 MB
    _Float16* gp  = (_Float16*)d_ws;
    float*    xs  = (float*)(gp + (size_t)SEQ * NBATCH * 40);
    float*    P   = xs + (size_t)SEQ * NBATCH;
    unsigned* MMu = (unsigned*)(P + 2 * 256 * NBATCH);
    float*    Wpp = (float*)(MMu + 1280);

    wprep_kernel<<<1, 256, 0, stream>>>(Wih_f, bih_f, bhh_f,
                                        Wih_r, bih_r, bhh_r, Wpp, MMu);
    max_kernel<<<4 * NBATCH, 256, 0, stream>>>(x, w4, w5, w6, w7, w8, MMu);
    // forward direction
    gprep_kernel<<<SEQ, 256, 0, stream>>>(x, w4, w5, w6, w7, w8, MMu, Wpp,
                                          gp, xs, 0);
    lstm_kernel<<<1024, 64, 0, stream>>>(gp, xs, Whh_f, P);
    // reverse direction (reuses gp/xs buffers; stream-ordered)
    gprep_kernel<<<SEQ, 256, 0, stream>>>(x, w4, w5, w6, w7, w8, MMu, Wpp,
                                          gp, xs, 1);
    lstm_kernel<<<1024, 64, 0, stream>>>(gp, xs, Whh_r, P + 256 * NBATCH);
    final_kernel<<<1, NBATCH, 0, stream>>>(P, (float*)d_out);
}